// Round 3
// baseline (17962.097 us; speedup 1.0000x reference)
//
#include <hip/hip_runtime.h>
#include <hip/hip_cooperative_groups.h>
#include <cmath>

namespace cg = cooperative_groups;

typedef _Float16 f16;
typedef _Float16 f16x8 __attribute__((ext_vector_type(8)));
typedef _Float16 f16x4 __attribute__((ext_vector_type(4)));
typedef float f32x4 __attribute__((ext_vector_type(4)));

#define H_DIM 1024
#define I_DIMM 256
#define B_DIM 64
#define T_DIM 256
#define K_DIM 1280

// Build W16[4096][1280] = fp16([Whh | Wih]) row-major. grid = 4096 blocks.
__global__ __launch_bounds__(256) void conv_w_kernel(const float* __restrict__ Whh,
                                                     const float* __restrict__ Wih,
                                                     f16* __restrict__ W16) {
    const int r = blockIdx.x;
    const int tid = threadIdx.x;
    const float* hh = Whh + (size_t)r * H_DIM;
    const float* ih = Wih + (size_t)r * I_DIMM;
    f16* dst = W16 + (size_t)r * K_DIM;
    for (int k = tid; k < K_DIM; k += 256)
        dst[k] = (f16)(k < H_DIM ? hh[k] : ih[k - H_DIM]);
}

// x fp32 -> fp16, vectorized 4-wide. n4 = total/4.
__global__ __launch_bounds__(256) void conv_x_kernel(const float* __restrict__ x,
                                                     f16* __restrict__ x16, int n4) {
    const int i = blockIdx.x * 256 + threadIdx.x;
    if (i < n4) {
        float4 v = ((const float4*)x)[i];
        f16x4 o;
        o[0] = (f16)v.x; o[1] = (f16)v.y; o[2] = (f16)v.z; o[3] = (f16)v.w;
        ((f16x4*)x16)[i] = o;
    }
}

// Persistent LSTM: both directions, all 512 timesteps, one launch.
// grid = 256 blocks x 256 threads (1 block/CU). Block owns h-cols
// [blk*4, blk*4+4) x 4 gates = 16 W rows, whose fp16 fragments live in
// VGPRs (40 x f16x8 per lane) for the whole phase. Cell state c lives in a
// register of the activation thread and carries enc -> dec.
// Per wave: D[16 batch x 16 gate] over K=1280, layouts identical to the
// round-2 verified kernel.
__global__ __launch_bounds__(256, 1) void lstm_persistent(
    f16* __restrict__ h0,            // [64][1024] ping
    f16* __restrict__ h1,            // [64][1024] pong
    const f16* __restrict__ x16,     // [64][256][256]
    const f16* __restrict__ W16e,    // [4096][1280]
    const f16* __restrict__ W16d,    // [4096][1280]
    const float* __restrict__ enc_bih, const float* __restrict__ enc_bhh,
    const float* __restrict__ dec_bih, const float* __restrict__ dec_bhh)
{
    __shared__ float gl[64][17];
    cg::grid_group grid = cg::this_grid();

    const int tid  = threadIdx.x;
    const int blk  = blockIdx.x;
    const int w    = tid >> 6;
    const int lane = tid & 63;
    const int n    = lane & 15;
    const int kg   = lane >> 4;

    const int rW = (n >> 2) * H_DIM + blk * 4 + (n & 3);  // this lane's W row
    const int bA = w * 16 + n;                            // this lane's batch row (A operand)

    // activation-thread mapping: thread -> (batch ab, h-col acol)
    const int ab   = tid >> 2;
    const int aj   = tid & 3;
    const int acol = blk * 4 + aj;

    float c_reg = 0.f;   // cell state for (ab, acol); carries across enc->dec

    #pragma unroll 1
    for (int phase = 0; phase < 2; ++phase) {
        const f16* W = phase ? W16d : W16e;
        const float* bi = phase ? dec_bih : enc_bih;
        const float* bh = phase ? dec_bhh : enc_bhh;

        // pre-summed biases for the activation thread
        float bsum[4];
        #pragma unroll
        for (int g = 0; g < 4; ++g)
            bsum[g] = bi[g * H_DIM + acol] + bh[g * H_DIM + acol];

        // pin this lane's 40 B-fragments (full K=1280) in VGPRs
        f16x8 wr_[40];
        {
            const f16* pw = W + (size_t)rW * K_DIM + kg * 8;
            #pragma unroll
            for (int it = 0; it < 40; ++it)
                wr_[it] = *(const f16x8*)(pw + it * 32);
        }

        #pragma unroll 1
        for (int t = 0; t < T_DIM; ++t) {
            const f16* hi = (t & 1) ? h1 : h0;
            f16*       ho = (t & 1) ? h0 : h1;
            const f16* pa = hi + (size_t)bA * H_DIM + kg * 8;
            const f16* px = x16 + (size_t)bA * (T_DIM * I_DIMM) + t * I_DIMM + kg * 8;

            f32x4 acc[4];
            #pragma unroll
            for (int q = 0; q < 4; ++q) acc[q] = (f32x4){0.f, 0.f, 0.f, 0.f};

            // h part: k in [0,1024)
            #pragma unroll
            for (int it = 0; it < 32; ++it) {
                f16x8 a = *(const f16x8*)(pa + it * 32);
                acc[it & 3] = __builtin_amdgcn_mfma_f32_16x16x32_f16(a, wr_[it], acc[it & 3], 0, 0, 0);
            }
            // x part: k in [1024,1280)
            #pragma unroll
            for (int it = 0; it < 8; ++it) {
                f16x8 a = *(const f16x8*)(px + it * 32);
                acc[it & 3] = __builtin_amdgcn_mfma_f32_16x16x32_f16(a, wr_[32 + it], acc[it & 3], 0, 0, 0);
            }
            f32x4 s = acc[0] + acc[1] + acc[2] + acc[3];
            #pragma unroll
            for (int r = 0; r < 4; ++r)
                gl[w * 16 + kg * 4 + r][n] = s[r];
            __syncthreads();

            // activations + state update
            float pre[4];
            #pragma unroll
            for (int g = 0; g < 4; ++g)
                pre[g] = gl[ab][g * 4 + aj] + bsum[g];
            const float i_ = 1.f / (1.f + expf(-pre[0]));
            const float f_ = 1.f / (1.f + expf(-pre[1]));
            const float g_ = tanhf(pre[2]);
            const float o_ = 1.f / (1.f + expf(-pre[3]));
            c_reg = f_ * c_reg + i_ * g_;
            ho[(size_t)ab * H_DIM + acol] = (f16)(o_ * tanhf(c_reg));

            grid.sync();   // publishes h_out; also orders gl reuse
        }
    }
}

// Tail MLP: a = PReLU(additional @ fcc_W^T + fcc_b); out[b] = [dh, a] @ fc_W^T + fc_b
__global__ __launch_bounds__(256) void tail_kernel(
    const f16* __restrict__ dh,        // [64][1024] fp16
    const float* __restrict__ addl,    // [64][128]
    const float* __restrict__ fccW,    // [256][128]
    const float* __restrict__ fccb,    // [256]
    const float* __restrict__ fcW,     // [1][1280]
    const float* __restrict__ fcb,     // [1]
    const float* __restrict__ prelu_a, // [1]
    float* __restrict__ out)           // [64]
{
    __shared__ float a_lds[256];
    __shared__ float red[256];
    const int b = blockIdx.x;
    const int t = threadIdx.x;

    float s = fccb[t];
    const float* wr = fccW + t * 128;
    const float* ar = addl + b * 128;
    #pragma unroll 4
    for (int k = 0; k < 128; ++k) s += ar[k] * wr[k];
    const float pa = *prelu_a;
    a_lds[t] = (s >= 0.f) ? s : pa * s;
    __syncthreads();

    float acc = 0.f;
    for (int k = t; k < 1024; k += 256) acc += (float)dh[b * H_DIM + k] * fcW[k];
    acc += a_lds[t] * fcW[1024 + t];
    red[t] = acc;
    __syncthreads();
    for (int sft = 128; sft > 0; sft >>= 1) {
        if (t < sft) red[t] += red[t + sft];
        __syncthreads();
    }
    if (t == 0) out[b] = red[0] + fcb[0];
}

extern "C" void kernel_launch(void* const* d_in, const int* in_sizes, int n_in,
                              void* d_out, int out_size, void* d_ws, size_t ws_size,
                              hipStream_t stream)
{
    const float* x       = (const float*)d_in[0];
    const float* addl    = (const float*)d_in[1];
    const float* enc_Wih = (const float*)d_in[2];
    const float* enc_Whh = (const float*)d_in[3];
    const float* enc_bih = (const float*)d_in[4];
    const float* enc_bhh = (const float*)d_in[5];
    const float* dec_Wih = (const float*)d_in[6];
    const float* dec_Whh = (const float*)d_in[7];
    const float* dec_bih = (const float*)d_in[8];
    const float* dec_bhh = (const float*)d_in[9];
    const float* fcc_W   = (const float*)d_in[10];
    const float* fcc_b   = (const float*)d_in[11];
    const float* fc_W    = (const float*)d_in[12];
    const float* fc_b    = (const float*)d_in[13];
    const float* prelu_a = (const float*)d_in[14];

    char* wsb = (char*)d_ws;
    const size_t W16_BYTES = (size_t)4 * H_DIM * K_DIM * sizeof(f16);   // 10.5 MB
    const size_t X16_BYTES = (size_t)B_DIM * T_DIM * I_DIMM * sizeof(f16);
    const size_t H16_BYTES = (size_t)B_DIM * H_DIM * sizeof(f16);

    f16* W16e = (f16*)wsb;                      wsb += W16_BYTES;
    f16* W16d = (f16*)wsb;                      wsb += W16_BYTES;
    f16* x16  = (f16*)wsb;                      wsb += X16_BYTES;
    f16* h0   = (f16*)wsb;                      wsb += H16_BYTES;
    f16* h1   = (f16*)wsb;

    // One-time (per call) conversions.
    conv_w_kernel<<<4 * H_DIM, 256, 0, stream>>>(enc_Whh, enc_Wih, W16e);
    conv_w_kernel<<<4 * H_DIM, 256, 0, stream>>>(dec_Whh, dec_Wih, W16d);
    conv_x_kernel<<<(B_DIM * T_DIM * I_DIMM / 4 + 255) / 256, 256, 0, stream>>>(
        x, x16, B_DIM * T_DIM * I_DIMM / 4);
    hipMemsetAsync(h0, 0, H16_BYTES, stream);

    // Persistent cooperative kernel: both LSTMs, 512 steps, one launch.
    {
        void* args[] = { &h0, &h1, &x16, &W16e, &W16d,
                         &enc_bih, &enc_bhh, &dec_bih, &dec_bhh };
        hipLaunchCooperativeKernel((void*)lstm_persistent, dim3(256), dim3(256),
                                   args, 0, stream);
    }

    // Final dec h is in h0 (256 steps per phase, even count).
    tail_kernel<<<64, 256, 0, stream>>>(h0, addl, fcc_W, fcc_b, fc_W, fc_b,
                                        prelu_a, (float*)d_out);
}